// Round 7
// baseline (858.684 us; speedup 1.0000x reference)
//
#include <hip/hip_runtime.h>
#include <hip/hip_bf16.h>
#include <stdint.h>
#include <algorithm>

// Sparse conv encoder, MFMA gather-GEMM, barrier-free inner loop.
// R6 postmortem: mconv was latency/barrier-bound (MfmaUtil 12%, VALU 19%,
// HBM 19%, occ 21%, 18 syncthreads/block at 2 blocks/CU). Fix: load MFMA
// A-fragments straight from global bf16 features (per-lane gather, LLC-hot)
// and B-fragments from a pre-transposed bf16 weight table (L2-hot, shared by
// all blocks) -> NO __syncthreads in the k-loop, LDS ~5KB (gather indices
// only), occupancy VGPR-limited (launch_bounds(256,3)).
// Requires bf16 inputs -> d0/d1 write fp32 to d_out AND bf16 shadow to ws.
// Tiered ws fallbacks: T3 full direct chain (~112MB), T2 direct for bf16-in
// layers + R6 LDS-staged for c1/c2 (~63MB), T1 = R6, T0 = R5 (bsearch).

#define DI __device__ __forceinline__

typedef __attribute__((ext_vector_type(8))) short bf16x8;
typedef __attribute__((ext_vector_type(4))) float f32x4;

DI float u2f(uint32_t u){ union{uint32_t i;float f;}v; v.i=u; return v.f; }
DI uint16_t f2bf(float x){
  union{float f;uint32_t i;}v; v.f=x;
  uint32_t r = v.i + 0x7fffu + ((v.i>>16)&1u);
  return (uint16_t)(r>>16);
}
DI uint32_t pack2(float a, float b){
  return (uint32_t)f2bf(a) | ((uint32_t)f2bf(b) << 16);
}

DI int bsearch_row(const int* __restrict__ om, int M, int row){
  int lo = 0, hi = M;
  while (lo < hi){ int mid = (lo+hi)>>1; if (om[mid] < row) lo = mid+1; else hi = mid; }
  return (lo < M && om[lo] == row) ? lo : -1;
}

__global__ __launch_bounds__(256) void diag_kernel(float* __restrict__ out, long n, float c){
  long i = (long)blockIdx.x*256 + threadIdx.x;
  if (i < n) out[i] = c;
}

__global__ __launch_bounds__(256) void init_table_kernel(int* __restrict__ t, long n){
  long i = (long)blockIdx.x*256 + threadIdx.x;
  if (i < n) t[i] = -1;
}

__global__ __launch_bounds__(256) void build_table_kernel(
    const int* __restrict__ im, const int* __restrict__ om,
    int* __restrict__ tab, int M, int n_in, int n_out){
  const int k = blockIdx.y;
  long t = (long)blockIdx.x*256 + threadIdx.x;
  if (t >= M) return;
  int ii = im[(long)k*M + t];
  int oo = om[(long)k*M + t];
  if (ii >= 0 && ii < n_in && oo >= 0 && oo < n_out)
    tab[(long)k*n_out + oo] = ii;
}

// w (9,cin,128) fp32 -> wtb (9,128,cin) bf16 (transposed B rows).
__global__ __launch_bounds__(256) void prep_w_kernel(
    const float* __restrict__ w, uint16_t* __restrict__ wtb, int cin){
  long idx = (long)blockIdx.x*256 + threadIdx.x;
  long total = 9L*128*cin;
  if (idx >= total) return;
  int k = (int)(idx / (128*cin));
  int rem = (int)(idx % (128*cin));
  int cout = rem / cin, ci = rem % cin;
  wtb[idx] = f2bf(w[((long)k*cin + ci)*128 + cout]);
}

// c0 via table: thread = row.
__global__ __launch_bounds__(256) void c0_tab_kernel(
    const float* __restrict__ feats, const float* __restrict__ w,
    const float* __restrict__ bias, const int* __restrict__ tab,
    uint16_t* __restrict__ out, int n_out){
  __shared__ float w_s[576];
  __shared__ float b_s[64];
  const int tid = threadIdx.x;
  for (int i = tid; i < 576; i += 256) w_s[i] = w[i];
  if (tid < 64) b_s[tid] = bias[tid];
  __syncthreads();
  long r = (long)blockIdx.x*256 + tid;
  if (r >= n_out) return;
  float f[9];
  #pragma unroll
  for (int k = 0; k < 9; k++){
    int gi = tab[(long)k*n_out + r];
    f[k] = (gi >= 0) ? feats[gi] : 0.f;
  }
  uint16_t* dst = out + r*64;
  #pragma unroll
  for (int c0 = 0; c0 < 64; c0 += 16){
    float a[16];
    #pragma unroll
    for (int j = 0; j < 16; j++) a[j] = b_s[c0+j];
    #pragma unroll
    for (int k = 0; k < 9; k++){
      float fk = f[k];
      #pragma unroll
      for (int j = 0; j < 16; j++) a[j] += fk * w_s[k*64 + c0 + j];
    }
    uint4 o0, o1;
    o0.x = pack2(a[0],a[1]);   o0.y = pack2(a[2],a[3]);
    o0.z = pack2(a[4],a[5]);   o0.w = pack2(a[6],a[7]);
    o1.x = pack2(a[8],a[9]);   o1.y = pack2(a[10],a[11]);
    o1.z = pack2(a[12],a[13]); o1.w = pack2(a[14],a[15]);
    *(uint4*)(dst + c0)     = o0;
    *(uint4*)(dst + c0 + 8) = o1;
  }
}

// c0 fallback (binary search).
__global__ __launch_bounds__(256) void gconv_c0_kernel(
    const float* __restrict__ feats, const float* __restrict__ w,
    const float* __restrict__ bias,
    const int* __restrict__ im, const int* __restrict__ om, int M,
    uint16_t* __restrict__ out, int n_in, int n_out){
  __shared__ float w_s[576];
  __shared__ int gi_s[36];
  const int tid = threadIdx.x;
  for (int i = tid; i < 576; i += 256) w_s[i] = w[i];
  const int base = blockIdx.x * 4;
  if (tid < 36){
    int p = tid / 9, k = tid - p*9;
    int row = base + p, gi = -1;
    if (row < n_out){
      int pos = bsearch_row(om + (long)k*M, M, row);
      if (pos >= 0){
        int ii = im[(long)k*M + pos];
        if (ii >= 0 && ii < n_in) gi = ii;
      }
    }
    gi_s[p*9 + k] = gi;
  }
  __syncthreads();
  int r4 = tid >> 6, c = tid & 63;
  int row = base + r4;
  if (row >= n_out) return;
  float a = bias[c];
  #pragma unroll
  for (int k = 0; k < 9; k++){
    int gi = gi_s[r4*9 + k];
    if (gi >= 0) a += feats[gi] * w_s[k*64 + c];
  }
  out[(long)row*64 + c] = f2bf(a);
}

// ---------------- direct (barrier-free) MFMA gather conv ----------------
// A from global bf16 via gather table; B from global bf16 wtb (L2-hot).
// OMODE: 0 = fp32 only, 1 = bf16 only, 2 = both.
template<int CIN, bool RELU, int OMODE>
__global__ __launch_bounds__(256,3) void mconv_direct(
    const uint16_t* __restrict__ fin,     // (n_in, CIN) bf16
    const uint16_t* __restrict__ wtb,     // (9,128,CIN) bf16
    const float* __restrict__ bias,
    const int* __restrict__ tab,          // (9, n_out)
    float* __restrict__ out_f, uint16_t* __restrict__ out_b,
    int n_out){
  const int tid = threadIdx.x;
  const int rb  = blockIdx.x * 128;
  __shared__ int gi_s[9*128];
  __shared__ int kval[9];

  if (tid < 9) kval[tid] = 0;
  __syncthreads();
  for (int idx = tid; idx < 9*128; idx += 256){
    int k = idx >> 7, r = idx & 127;
    int row = rb + r, gi = -1;
    if (row < n_out) gi = tab[(long)k*n_out + row];
    gi_s[idx] = gi;
    if (gi >= 0) kval[k] = 1;   // benign race
  }
  __syncthreads();

  const int lane = tid & 63;
  const int wv   = tid >> 6;
  const int wr   = (wv & 1) * 64;
  const int wc   = (wv >> 1) * 64;
  const int l16  = lane & 15;
  const int quad = lane >> 4;

  f32x4 acc[4][4];
  #pragma unroll
  for (int i = 0; i < 4; i++)
    #pragma unroll
    for (int j = 0; j < 4; j++)
      acc[i][j] = (f32x4){0.f,0.f,0.f,0.f};

  // B row pointers (k-invariant part)
  const uint16_t* wrow[4];
  #pragma unroll
  for (int ct = 0; ct < 4; ct++)
    wrow[ct] = wtb + (long)(wc + ct*16 + l16)*CIN + quad*8;

  for (int k = 0; k < 9; k++){
    if (!kval[k]) continue;
    long gofs[4];
    #pragma unroll
    for (int t = 0; t < 4; t++){
      int gi = gi_s[(k<<7) + wr + t*16 + l16];
      gofs[t] = (gi >= 0) ? (long)gi*CIN + quad*8 : -1;
    }
    const long wk = (long)k*128*CIN;
    #pragma unroll
    for (int ch = 0; ch < CIN/32; ch++){
      bf16x8 af[4], bfr[4];
      #pragma unroll
      for (int t = 0; t < 4; t++){
        af[t] = (gofs[t] >= 0)
          ? *(const bf16x8*)(fin + gofs[t] + ch*32)
          : (bf16x8){0,0,0,0,0,0,0,0};
      }
      #pragma unroll
      for (int ct = 0; ct < 4; ct++)
        bfr[ct] = *(const bf16x8*)(wrow[ct] + wk + ch*32);
      #pragma unroll
      for (int rt = 0; rt < 4; rt++)
        #pragma unroll
        for (int ct = 0; ct < 4; ct++)
          acc[rt][ct] = __builtin_amdgcn_mfma_f32_16x16x32_bf16(
              af[rt], bfr[ct], acc[rt][ct], 0, 0, 0);
    }
  }

  #pragma unroll
  for (int ct = 0; ct < 4; ct++){
    int cout = wc + ct*16 + l16;
    float bv = bias[cout];
    #pragma unroll
    for (int rt = 0; rt < 4; rt++){
      #pragma unroll
      for (int r = 0; r < 4; r++){
        int row = rb + wr + rt*16 + quad*4 + r;
        if (row < n_out){
          float v = acc[rt][ct][r] + bv;
          if (RELU) v = v > 0.f ? v : 0.f;
          if (OMODE == 0 || OMODE == 2) out_f[(long)row*128 + cout] = v;
          if (OMODE == 1 || OMODE == 2) out_b[(long)row*128 + cout] = f2bf(v);
        }
      }
    }
  }
}

// ---------------- LDS-staged MFMA gather conv (R6, fallback + fp32-in) ----
template<int CIN, bool RELU, bool INBF, bool OUTBF>
__global__ __launch_bounds__(256,2) void mconv_kernel(
    const void* __restrict__ feats_v, const float* __restrict__ w,
    const uint16_t* __restrict__ wtb, int use_wtb,
    const float* __restrict__ bias,
    const int* __restrict__ im, const int* __restrict__ om, int M,
    const int* __restrict__ tab, int use_tab,
    void* __restrict__ out_v, int n_in, int n_out){
  const int tid = threadIdx.x;
  const int rb  = blockIdx.x * 128;
  constexpr int FS = CIN + 8;

  __shared__ __align__(16) uint16_t f_s[128*FS];
  __shared__ __align__(16) uint16_t wt_s[128*FS];
  __shared__ int gi_s[9*128];
  __shared__ int kval[9];

  if (tid < 9) kval[tid] = 0;
  __syncthreads();
  for (int idx = tid; idx < 9*128; idx += 256){
    int k = idx >> 7, r = idx & 127;
    int row = rb + r, gi = -1;
    if (row < n_out){
      if (use_tab){
        gi = tab[(long)k*n_out + row];
      } else {
        int pos = bsearch_row(om + (long)k*M, M, row);
        if (pos >= 0){
          int ii = im[(long)k*M + pos];
          if (ii >= 0 && ii < n_in) gi = ii;
        }
      }
    }
    gi_s[idx] = gi;
    if (gi >= 0) kval[k] = 1;
  }
  __syncthreads();

  const int lane = tid & 63;
  const int wv   = tid >> 6;
  const int wr   = (wv & 1) * 64;
  const int wc   = (wv >> 1) * 64;
  const int l16  = lane & 15;
  const int quad = lane >> 4;

  f32x4 acc[4][4];
  #pragma unroll
  for (int i = 0; i < 4; i++)
    #pragma unroll
    for (int j = 0; j < 4; j++)
      acc[i][j] = (f32x4){0.f,0.f,0.f,0.f};

  for (int k = 0; k < 9; k++){
    if (!kval[k]) continue;
    if (use_wtb){
      const uint4* wg = (const uint4*)(wtb + (long)k*128*CIN);
      #pragma unroll
      for (int idx = tid; idx < 128*CIN/8; idx += 256){
        int cout = idx/(CIN/8), seg = idx%(CIN/8);
        *(uint4*)(&wt_s[cout*FS + seg*8]) = wg[idx];
      }
    } else {
      const float4* wg = (const float4*)(w + (long)k*CIN*128);
      #pragma unroll
      for (int idx = tid; idx < CIN*32; idx += 256){
        int ci = idx >> 5, c4 = (idx & 31)*4;
        float4 v = wg[idx];
        wt_s[(c4+0)*FS + ci] = f2bf(v.x);
        wt_s[(c4+1)*FS + ci] = f2bf(v.y);
        wt_s[(c4+2)*FS + ci] = f2bf(v.z);
        wt_s[(c4+3)*FS + ci] = f2bf(v.w);
      }
    }
    if (INBF){
      const uint16_t* f = (const uint16_t*)feats_v;
      #pragma unroll
      for (int idx = tid; idx < 128*CIN/8; idx += 256){
        int r = idx/(CIN/8), seg = idx%(CIN/8);
        int gi = gi_s[(k<<7)+r];
        uint4 v = make_uint4(0,0,0,0);
        if (gi >= 0) v = *(const uint4*)(f + (long)gi*CIN + seg*8);
        *(uint4*)(&f_s[r*FS + seg*8]) = v;
      }
    } else {
      const float* f = (const float*)feats_v;
      #pragma unroll
      for (int idx = tid; idx < 128*CIN/8; idx += 256){
        int r = idx/(CIN/8), seg = idx%(CIN/8);
        int gi = gi_s[(k<<7)+r];
        uint4 o = make_uint4(0,0,0,0);
        if (gi >= 0){
          float4 v0 = *(const float4*)(f + (long)gi*CIN + seg*8);
          float4 v1 = *(const float4*)(f + (long)gi*CIN + seg*8 + 4);
          o.x = pack2(v0.x,v0.y); o.y = pack2(v0.z,v0.w);
          o.z = pack2(v1.x,v1.y); o.w = pack2(v1.z,v1.w);
        }
        *(uint4*)(&f_s[r*FS + seg*8]) = o;
      }
    }
    __syncthreads();

    #pragma unroll
    for (int ch = 0; ch < CIN/32; ch++){
      bf16x8 af[4], bfr[4];
      #pragma unroll
      for (int t = 0; t < 4; t++){
        af[t]  = *(const bf16x8*)(&f_s [(wr + t*16 + l16)*FS + ch*32 + quad*8]);
        bfr[t] = *(const bf16x8*)(&wt_s[(wc + t*16 + l16)*FS + ch*32 + quad*8]);
      }
      #pragma unroll
      for (int rt = 0; rt < 4; rt++)
        #pragma unroll
        for (int ct = 0; ct < 4; ct++)
          acc[rt][ct] = __builtin_amdgcn_mfma_f32_16x16x32_bf16(
              af[rt], bfr[ct], acc[rt][ct], 0, 0, 0);
    }
    __syncthreads();
  }

  #pragma unroll
  for (int ct = 0; ct < 4; ct++){
    int cout = wc + ct*16 + l16;
    float bv = bias[cout];
    #pragma unroll
    for (int rt = 0; rt < 4; rt++){
      #pragma unroll
      for (int r = 0; r < 4; r++){
        int row = rb + wr + rt*16 + quad*4 + r;
        if (row < n_out){
          float v = acc[rt][ct][r] + bv;
          if (RELU) v = v > 0.f ? v : 0.f;
          if (OUTBF) ((uint16_t*)out_v)[(long)row*128 + cout] = f2bf(v);
          else       ((float*)   out_v)[(long)row*128 + cout] = v;
        }
      }
    }
  }
}

static inline long cdivl(long a, long b){ return (a + b - 1) / b; }
static inline long alg(long b){ return (b + 255)/256*256; }

extern "C" void kernel_launch(void* const* d_in, const int* in_sizes, int n_in_args,
                              void* d_out, int out_size, void* d_ws, size_t ws_size,
                              hipStream_t stream) {
  const float* feats = (const float*)d_in[0];
  const float* w_c0 = (const float*)d_in[1];
  const float* b_c0 = (const float*)d_in[2];
  const int* in_c0  = (const int*)d_in[3];
  const int* out_c0 = (const int*)d_in[4];
  const float* w_d0 = (const float*)d_in[5];
  const float* b_d0 = (const float*)d_in[6];
  const int* in_d0  = (const int*)d_in[7];
  const int* out_d0 = (const int*)d_in[8];
  const float* w_c1 = (const float*)d_in[9];
  const float* b_c1 = (const float*)d_in[10];
  const int* in_c1  = (const int*)d_in[11];
  const int* out_c1 = (const int*)d_in[12];
  const float* w_d1 = (const float*)d_in[13];
  const float* b_d1 = (const float*)d_in[14];
  const int* in_d1  = (const int*)d_in[15];
  const int* out_d1 = (const int*)d_in[16];
  const float* w_c2 = (const float*)d_in[17];
  const float* b_c2 = (const float*)d_in[18];
  const int* in_c2  = (const int*)d_in[19];
  const int* out_c2 = (const int*)d_in[20];
  const float* w_d2 = (const float*)d_in[21];
  const float* b_d2 = (const float*)d_in[22];
  const int* in_d2  = (const int*)d_in[23];
  const int* out_d2 = (const int*)d_in[24];

  const int n0   = in_sizes[0];
  const int M_c0 = in_sizes[3]  / 9;
  const int M_d0 = in_sizes[7]  / 9;
  const int M_c1 = in_sizes[11] / 9;
  const int M_d1 = in_sizes[15] / 9;
  const int M_c2 = in_sizes[19] / 9;
  const int M_d2 = in_sizes[23] / 9;
  const int n1   = M_c1;
  const int n2   = M_c2;
  const int n3   = out_size/128 - n1 - n2;

  bool sane = n0 > 0 && out_size % 128 == 0 &&
              M_c0 > 0 && M_d0 > 0 && M_d1 > 0 && M_d2 > 0 &&
              n1 > 0 && n2 > 0 && n3 > 0;
  if (!sane){
    diag_kernel<<<cdivl(out_size,256),256,0,stream>>>((float*)d_out, out_size, 1e30f);
    return;
  }

  long bufAelems = std::max((long)n0*64, std::max((long)n1*128, (long)n2*128));
  long bufAbytes = alg(bufAelems*2);
  long bufBbytes = alg((long)n1*128*2);
  long tbytes = alg(9L*n0*4);
  long wt64  = 9L*128*64, wt128 = 9L*128*128;
  long wbytes = alg((wt64 + 4*wt128)*2);

  char* p = (char*)d_ws;
  int* table = (int*)p;                       p += tbytes;
  uint16_t* wtb_d0 = (uint16_t*)p;
  uint16_t* wtb_c1 = wtb_d0 + wt64;
  uint16_t* wtb_d1 = wtb_c1 + wt128;
  uint16_t* wtb_c2 = wtb_d1 + wt128;
  uint16_t* wtb_d2 = wtb_c2 + wt128;          p += wbytes;
  uint16_t* bufA = (uint16_t*)p;              p += bufAbytes;
  uint16_t* bufB = (uint16_t*)p;

  int tier;
  if      (ws_size >= (size_t)(tbytes + wbytes + bufAbytes + bufBbytes + 256)) tier = 3;
  else if (ws_size >= (size_t)(tbytes + wbytes + bufAbytes + 256))             tier = 2;
  else if (ws_size >= (size_t)(tbytes + bufAbytes + 256)){
    tier = 1;
    bufA = (uint16_t*)((char*)d_ws + tbytes);   // no wtb region in tier 1
  } else if (ws_size >= (size_t)bufAbytes + 256){
    tier = 0;
    bufA = (uint16_t*)d_ws;
  } else {
    diag_kernel<<<cdivl(out_size,256),256,0,stream>>>(
        (float*)d_out, out_size, (float)(16 + (int)(ws_size>>20)));
    return;
  }

  float* out2 = (float*)d_out;
  float* out1 = out2 + (long)n3*128;
  float* out0 = out1 + (long)n2*128;

  auto make_tab = [&](const int* im, const int* om, int M, int n_in, int n_out){
    long n = 9L*n_out;
    init_table_kernel<<<cdivl(n,256),256,0,stream>>>(table, n);
    dim3 g((unsigned)cdivl(M,256), 9);
    build_table_kernel<<<g,256,0,stream>>>(im, om, table, M, n_in, n_out);
  };

  if (tier >= 2){
    prep_w_kernel<<<cdivl(9L*128*64,256),256,0,stream>>>(w_d0, wtb_d0, 64);
    prep_w_kernel<<<cdivl(9L*128*128,256),256,0,stream>>>(w_c1, wtb_c1, 128);
    prep_w_kernel<<<cdivl(9L*128*128,256),256,0,stream>>>(w_d1, wtb_d1, 128);
    prep_w_kernel<<<cdivl(9L*128*128,256),256,0,stream>>>(w_c2, wtb_c2, 128);
    prep_w_kernel<<<cdivl(9L*128*128,256),256,0,stream>>>(w_d2, wtb_d2, 128);
  }

  if (tier == 3){
    uint16_t* x = bufA; uint16_t* y = bufA; uint16_t* z = bufA;
    uint16_t* o0b = bufB; uint16_t* o1b = bufB;
    make_tab(in_c0, out_c0, M_c0, n0, n0);
    c0_tab_kernel<<<cdivl(n0,256),256,0,stream>>>(feats, w_c0, b_c0, table, x, n0);
    make_tab(in_d0, out_d0, M_d0, n0, n1);
    mconv_direct<64,true,2><<<cdivl(n1,128),256,0,stream>>>(
        x, wtb_d0, b_d0, table, out0, o0b, n1);
    make_tab(in_c1, out_c1, M_c1, n1, n1);
    mconv_direct<128,false,1><<<cdivl(n1,128),256,0,stream>>>(
        o0b, wtb_c1, b_c1, table, nullptr, y, n1);
    make_tab(in_d1, out_d1, M_d1, n1, n2);
    mconv_direct<128,true,2><<<cdivl(n2,128),256,0,stream>>>(
        y, wtb_d1, b_d1, table, out1, o1b, n2);
    make_tab(in_c2, out_c2, M_c2, n2, n2);
    mconv_direct<128,false,1><<<cdivl(n2,128),256,0,stream>>>(
        o1b, wtb_c2, b_c2, table, nullptr, z, n2);
    make_tab(in_d2, out_d2, M_d2, n2, n3);
    mconv_direct<128,false,0><<<cdivl(n3,128),256,0,stream>>>(
        z, wtb_d2, b_d2, table, out2, nullptr, n3);
  } else if (tier == 2){
    uint16_t* x = bufA; uint16_t* y = bufA; uint16_t* z = bufA;
    make_tab(in_c0, out_c0, M_c0, n0, n0);
    c0_tab_kernel<<<cdivl(n0,256),256,0,stream>>>(feats, w_c0, b_c0, table, x, n0);
    make_tab(in_d0, out_d0, M_d0, n0, n1);
    mconv_direct<64,true,0><<<cdivl(n1,128),256,0,stream>>>(
        x, wtb_d0, b_d0, table, out0, nullptr, n1);
    make_tab(in_c1, out_c1, M_c1, n1, n1);
    mconv_kernel<128,false,false,true><<<cdivl(n1,128),256,0,stream>>>(
        out0, w_c1, wtb_c1, 1, b_c1, in_c1, out_c1, M_c1, table, 1, y, n1, n1);
    make_tab(in_d1, out_d1, M_d1, n1, n2);
    mconv_direct<128,true,0><<<cdivl(n2,128),256,0,stream>>>(
        y, wtb_d1, b_d1, table, out1, nullptr, n2);
    make_tab(in_c2, out_c2, M_c2, n2, n2);
    mconv_kernel<128,false,false,true><<<cdivl(n2,128),256,0,stream>>>(
        out1, w_c2, wtb_c2, 1, b_c2, in_c2, out_c2, M_c2, table, 1, z, n2, n2);
    make_tab(in_d2, out_d2, M_d2, n2, n3);
    mconv_direct<128,false,0><<<cdivl(n3,128),256,0,stream>>>(
        z, wtb_d2, b_d2, table, out2, nullptr, n3);
  } else {
    // tier 1: tables, LDS-staged convs, in-kernel w transpose.
    // tier 0: bsearch everywhere (no table).
    int ut = (tier == 1) ? 1 : 0;
    uint16_t* x = bufA; uint16_t* y = bufA; uint16_t* z = bufA;
    if (ut){
      make_tab(in_c0, out_c0, M_c0, n0, n0);
      c0_tab_kernel<<<cdivl(n0,256),256,0,stream>>>(feats, w_c0, b_c0, table, x, n0);
    } else {
      gconv_c0_kernel<<<cdivl(n0,4),256,0,stream>>>(
          feats, w_c0, b_c0, in_c0, out_c0, M_c0, x, n0, n0);
    }
    if (ut) make_tab(in_d0, out_d0, M_d0, n0, n1);
    mconv_kernel<64,true,true,false><<<cdivl(n1,128),256,0,stream>>>(
        x, w_d0, nullptr, 0, b_d0, in_d0, out_d0, M_d0, table, ut, out0, n0, n1);
    if (ut) make_tab(in_c1, out_c1, M_c1, n1, n1);
    mconv_kernel<128,false,false,true><<<cdivl(n1,128),256,0,stream>>>(
        out0, w_c1, nullptr, 0, b_c1, in_c1, out_c1, M_c1, table, ut, y, n1, n1);
    if (ut) make_tab(in_d1, out_d1, M_d1, n1, n2);
    mconv_kernel<128,true,true,false><<<cdivl(n2,128),256,0,stream>>>(
        y, w_d1, nullptr, 0, b_d1, in_d1, out_d1, M_d1, table, ut, out1, n1, n2);
    if (ut) make_tab(in_c2, out_c2, M_c2, n2, n2);
    mconv_kernel<128,false,false,true><<<cdivl(n2,128),256,0,stream>>>(
        out1, w_c2, nullptr, 0, b_c2, in_c2, out_c2, M_c2, table, ut, z, n2, n2);
    if (ut) make_tab(in_d2, out_d2, M_d2, n2, n3);
    mconv_kernel<128,false,true,false><<<cdivl(n3,128),256,0,stream>>>(
        z, w_d2, nullptr, 0, b_d2, in_d2, out_d2, M_d2, table, ut, out2, n2, n3);
  }
}